// Round 7
// baseline (134.275 us; speedup 1.0000x reference)
//
#include <hip/hip_runtime.h>
#include <hip/hip_bf16.h>
#include <math.h>

#define D_MODEL 512
#define D_LOW   64
#define NBINS   39
#define LOG2E   1.4426950408889634f
#define LN2     0.6931471805599453f

typedef __attribute__((ext_vector_type(8))) short short8;
typedef __attribute__((ext_vector_type(4))) float floatx4;

// ---------------------------------------------------------------------------
// Kernel 1 (lnp): prep + lnproj fused. grid = (BN/16, 2) x 256 (4 waves).
// blockIdx.y = og: 0 -> outs 0..63 (U, scale=log2e), 1 -> outs 64..127 (V).
// Phase 1a: 4 waves cooperatively build the 16x512 bf16 A-tile in LDS
//   (wave wv converts kc = 4wv..4wv+3) + per-row LN partial stats.
// Phase 1b: each wave folds LN-affine into ITS OWN 16 weight rows directly
//   in MFMA B-fragment layout (lane(q,ln16) covers out=wv*16+ln16,
//   c=kc*32+q*8..+8) -> bfrag[16] registers. ws/sb reduced over q by shfl.
//   Kills the prep dispatch + the w2bf 128KB round trip entirely.
// Phase 2: 16 x (LDS A-frag + reg B-frag) MFMA; LN applied in epilogue.
// Only 768 waves exist -> fold VALU (~640/wave) is ~0.4 us aggregate.
// ---------------------------------------------------------------------------
__global__ __launch_bounds__(256) void lnp_kernel(
    const float* __restrict__ h_res,
    const float* __restrict__ ln_w, const float* __restrict__ ln_b,
    const float* __restrict__ wu_w, const float* __restrict__ wu_b,
    const float* __restrict__ wv_w, const float* __restrict__ wv_b,
    float* __restrict__ U, __hip_bfloat16* __restrict__ Vbf, int N) {
  __shared__ short abuf[16 * 512];          // [kc][q][ln16][8], 16 KB
  __shared__ float sred[4][2][16];          // per-wave (sum,ssq) row partials
  const int tid = threadIdx.x;
  const int wv = tid >> 6, lane = tid & 63;
  const int q = lane >> 4, ln16 = lane & 15;
  const int row0 = blockIdx.x * 16;
  const int og = blockIdx.y;                 // 0 = U half, 1 = V half

  // ---- phase 1a: A tile + stats (wave wv owns kc = 4wv .. 4wv+3) ----
  float sum = 0.f, ssq = 0.f;
  #pragma unroll
  for (int k2 = 0; k2 < 4; ++k2) {
    const int kc = wv * 4 + k2;
    const float* hp = h_res + (size_t)(row0 + ln16) * D_MODEL + kc * 32 + q * 8;
    const floatx4 x0 = *reinterpret_cast<const floatx4*>(hp);
    const floatx4 x1 = *reinterpret_cast<const floatx4*>(hp + 4);
    short8 a;
    #pragma unroll
    for (int e = 0; e < 4; ++e) {
      sum += x0[e]; ssq += x0[e] * x0[e];
      const __hip_bfloat16 hb = __float2bfloat16(x0[e]);
      a[e] = *reinterpret_cast<const short*>(&hb);
    }
    #pragma unroll
    for (int e = 0; e < 4; ++e) {
      sum += x1[e]; ssq += x1[e] * x1[e];
      const __hip_bfloat16 hb = __float2bfloat16(x1[e]);
      a[4 + e] = *reinterpret_cast<const short*>(&hb);
    }
    *reinterpret_cast<short8*>(&abuf[kc * 512 + q * 128 + ln16 * 8]) = a;
  }
  sum += __shfl_xor(sum, 16); sum += __shfl_xor(sum, 32);
  ssq += __shfl_xor(ssq, 16); ssq += __shfl_xor(ssq, 32);
  if (lane < 16) { sred[wv][0][ln16] = sum; sred[wv][1][ln16] = ssq; }

  // ---- phase 1b: fold weights into B-fragments (registers) ----
  const int oloc = wv * 16 + ln16;           // 0..63 within half
  const float scale = og ? 1.0f : LOG2E;
  const float* wrow = (og ? wv_w : wu_w) + (size_t)oloc * D_MODEL;
  short8 bfrag[16];
  float ws = 0.f, sb = 0.f;
  #pragma unroll
  for (int kc = 0; kc < 16; ++kc) {
    const int c0 = kc * 32 + q * 8;
    const floatx4 w0 = *reinterpret_cast<const floatx4*>(wrow + c0);
    const floatx4 w1 = *reinterpret_cast<const floatx4*>(wrow + c0 + 4);
    const floatx4 lw0 = *reinterpret_cast<const floatx4*>(ln_w + c0);
    const floatx4 lw1 = *reinterpret_cast<const floatx4*>(ln_w + c0 + 4);
    const floatx4 lb0 = *reinterpret_cast<const floatx4*>(ln_b + c0);
    const floatx4 lb1 = *reinterpret_cast<const floatx4*>(ln_b + c0 + 4);
    short8 f;
    #pragma unroll
    for (int e = 0; e < 4; ++e) {
      const float t0 = w0[e] * lw0[e] * scale;
      const __hip_bfloat16 h0 = __float2bfloat16(t0);
      f[e] = *reinterpret_cast<const short*>(&h0);
      ws += __bfloat162float(h0);
      sb += w0[e] * lb0[e];

      const float t1 = w1[e] * lw1[e] * scale;
      const __hip_bfloat16 h1 = __float2bfloat16(t1);
      f[4 + e] = *reinterpret_cast<const short*>(&h1);
      ws += __bfloat162float(h1);
      sb += w1[e] * lb1[e];
    }
    bfrag[kc] = f;
  }
  ws += __shfl_xor(ws, 16); ws += __shfl_xor(ws, 32);
  sb += __shfl_xor(sb, 16); sb += __shfl_xor(sb, 32);
  const float bb = scale * ((og ? wv_b[oloc] : wu_b[oloc]) + sb);

  __syncthreads();

  // ---- LN stats for the 4 C-rows this lane writes ----
  float mu_r[4], rs_r[4];
  #pragma unroll
  for (int r = 0; r < 4; ++r) {
    const int row = q * 4 + r;
    float s = 0.f, s2 = 0.f;
    #pragma unroll
    for (int w = 0; w < 4; ++w) { s += sred[w][0][row]; s2 += sred[w][1][row]; }
    const float mu  = s * (1.0f / (float)D_MODEL);
    const float var = s2 * (1.0f / (float)D_MODEL) - mu * mu;
    mu_r[r] = mu;
    rs_r[r] = rsqrtf(var + 1e-5f);
  }

  // ---- phase 2: MFMA over K ----
  floatx4 acc = (floatx4){0.f, 0.f, 0.f, 0.f};
  #pragma unroll
  for (int kc = 0; kc < 16; ++kc) {
    const short8 afr = *reinterpret_cast<const short8*>(
        &abuf[kc * 512 + q * 128 + ln16 * 8]);
    acc = __builtin_amdgcn_mfma_f32_16x16x32_bf16(afr, bfrag[kc], acc, 0, 0, 0);
  }

  #pragma unroll
  for (int r = 0; r < 4; ++r) {
    const int rowg = row0 + q * 4 + r;
    const float val = rs_r[r] * acc[r] - mu_r[r] * rs_r[r] * ws + bb;
    if (og == 0) {
      U[(size_t)rowg * D_LOW + oloc] = val;
    } else {
      Vbf[(size_t)rowg * D_LOW + oloc] = __float2bfloat16(val);
    }
  }
}

// ---------------------------------------------------------------------------
// Kernel 2 (pair): grid (N, 4B) x 256. Each wave = 1 i x 48 j (3 tiles).
// ILP-restructured vs r6: ALL 18 MFMAs first (f[3][3]), then 36 independent
// exp2 batched, then all 6 cross-lane shfls batched (2 steps x 3 parallel),
// then 3 logs batched — collapses 6 serial ~250cy epilogue chains into one
// overlapped pipeline (pair was pinned at 41us across 3 structures with
// VALUBusy ~45% and ~6us issue floor: exposed-latency-bound).
// Coop-LDS wfrag build (no wprep dispatch). No ticket (r4 lesson).
// ---------------------------------------------------------------------------
__global__ __launch_bounds__(256, 4) void pair_kernel(
    const float* __restrict__ U, const __hip_bfloat16* __restrict__ Vbf,
    const float* __restrict__ wb_w, const float* __restrict__ wb_b,
    const float* __restrict__ x_true, const float* __restrict__ pmask,
    float* __restrict__ part, int N) {
  __shared__ short wsh[6 * 64 * 8];         // 6 KB A-fragments for row i
  __shared__ float rbuf[8];
  const int i    = blockIdx.x;
  const int b    = blockIdx.y >> 2;
  const int qtr  = blockIdx.y & 3;
  const int tid  = threadIdx.x;
  const int wave = tid >> 6, lane = tid & 63;
  const int q = lane >> 4, ln16 = lane & 15;
  const int rowi = b * N + i;
  const int jbase = qtr * (N >> 2) + wave * (N >> 4);   // 48-j chunk per wave
  const int q4 = q * 4;

  // ---- V tiles up-front ----
  const short* Vp = reinterpret_cast<const short*>(Vbf) + (size_t)b * N * D_LOW;
  short8 v[3][2];
  #pragma unroll
  for (int tl = 0; tl < 3; ++tl) {
    const size_t jr = jbase + tl * 16 + ln16;
    v[tl][0] = *reinterpret_cast<const short8*>(Vp + jr * D_LOW + q * 8);
    v[tl][1] = *reinterpret_cast<const short8*>(Vp + jr * D_LOW + 32 + q * 8);
  }

  // ---- cooperative wfrag build (identical rounding to wprep) ----
  for (int slot = tid; slot < 384; slot += 256) {
    const int fidx = slot >> 6, l = slot & 63;
    const int t = fidx >> 1, s = fidx & 1;
    const int lq = l >> 4, l16 = l & 15;
    const int n = t * 16 + l16;
    short8 fr = (short8){0, 0, 0, 0, 0, 0, 0, 0};
    if (n < NBINS) {
      const float* up = U + (size_t)rowi * D_LOW + s * 32 + lq * 8;
      const float* wr = wb_w + (size_t)n * D_LOW + s * 32 + lq * 8;
      const floatx4 u0 = *reinterpret_cast<const floatx4*>(up);
      const floatx4 u1 = *reinterpret_cast<const floatx4*>(up + 4);
      const floatx4 w0 = *reinterpret_cast<const floatx4*>(wr);
      const floatx4 w1 = *reinterpret_cast<const floatx4*>(wr + 4);
      #pragma unroll
      for (int e = 0; e < 4; ++e) {
        const __hip_bfloat16 h0 = __float2bfloat16(u0[e] * w0[e]);
        const __hip_bfloat16 h1 = __float2bfloat16(u1[e] * w1[e]);
        fr[e]     = *reinterpret_cast<const short*>(&h0);
        fr[4 + e] = *reinterpret_cast<const short*>(&h1);
      }
    }
    *reinterpret_cast<short8*>(&wsh[slot * 8]) = fr;
  }

  // ---- tbin: 3 tiles ----
  const float xi0 = x_true[rowi * 3 + 0];
  const float xi1 = x_true[rowi * 3 + 1];
  const float xi2 = x_true[rowi * 3 + 2];
  const float pmi = pmask[rowi];
  const float BW  = (22.0f - 2.0f) / 38.0f;
  int tbv[3];
  #pragma unroll
  for (int tl = 0; tl < 3; ++tl) {
    const int rowj = b * N + jbase + tl * 16 + ln16;
    const float dx = xi0 - x_true[rowj * 3 + 0];
    const float dy = xi1 - x_true[rowj * 3 + 1];
    const float dz = xi2 - x_true[rowj * 3 + 2];
    const float d  = sqrtf(dx * dx + dy * dy + dz * dz);
    int tb = (int)((d - 2.0f) / BW);
    tb = tb < 0 ? 0 : (tb > NBINS - 1 ? NBINS - 1 : tb);
    tbv[tl] = (pmi * pmask[rowj] > 0.f) ? tb : -1;
  }

  floatx4 bias_init[3];
  #pragma unroll
  for (int t = 0; t < 3; ++t)
    #pragma unroll
    for (int r = 0; r < 4; ++r) {
      const int bin = t * 16 + q * 4 + r;
      bias_init[t][r] = (bin < NBINS) ? LOG2E * wb_b[bin] : -INFINITY;
    }

  __syncthreads();
  short8 wfrag[3][2];
  #pragma unroll
  for (int t = 0; t < 3; ++t)
    #pragma unroll
    for (int s = 0; s < 2; ++s)
      wfrag[t][s] = *reinterpret_cast<const short8*>(
          &wsh[((t * 2 + s) * 64 + lane) * 8]);

  // ---- all 18 MFMAs first ----
  floatx4 f[3][3];
  #pragma unroll
  for (int tl = 0; tl < 3; ++tl)
    #pragma unroll
    for (int t = 0; t < 3; ++t) {
      floatx4 a = bias_init[t];
      a = __builtin_amdgcn_mfma_f32_16x16x32_bf16(wfrag[t][0], v[tl][0], a, 0, 0, 0);
      a = __builtin_amdgcn_mfma_f32_16x16x32_bf16(wfrag[t][1], v[tl][1], a, 0, 0, 0);
      f[tl][t] = a;
    }

  // ---- batched exp2 + target extraction ----
  float sp[3], ltv[3];
  #pragma unroll
  for (int tl = 0; tl < 3; ++tl) {
    const int tbq = tbv[tl] - q4;
    float s0 = 0.f, s1 = 0.f, s2 = 0.f, s3 = 0.f, lt = 0.f;
    #pragma unroll
    for (int t = 0; t < 3; ++t) {
      const floatx4 fv = f[tl][t];
      s0 += __builtin_amdgcn_exp2f(fv[0]);
      s1 += __builtin_amdgcn_exp2f(fv[1]);
      s2 += __builtin_amdgcn_exp2f(fv[2]);
      s3 += __builtin_amdgcn_exp2f(fv[3]);
      lt += (tbq == t * 16 + 0) ? fv[0] : 0.f;
      lt += (tbq == t * 16 + 1) ? fv[1] : 0.f;
      lt += (tbq == t * 16 + 2) ? fv[2] : 0.f;
      lt += (tbq == t * 16 + 3) ? fv[3] : 0.f;
    }
    sp[tl] = (s0 + s1) + (s2 + s3);
    ltv[tl] = lt;
  }

  // ---- batched cross-lane reduces (2 steps x 3 independent) ----
  #pragma unroll
  for (int tl = 0; tl < 3; ++tl) sp[tl] += __shfl_xor(sp[tl], 16);
  #pragma unroll
  for (int tl = 0; tl < 3; ++tl) sp[tl] += __shfl_xor(sp[tl], 32);

  // ---- batched logs + accumulate ----
  float ce_sum = 0.f, cnt_sum = 0.f;
  #pragma unroll
  for (int tl = 0; tl < 3; ++tl) {
    const float ok = (tbv[tl] >= 0) ? 1.f : 0.f;
    ce_sum  += ok * LN2 * (__builtin_amdgcn_logf(sp[tl]) - 4.0f * ltv[tl]);
    cnt_sum += ok;
  }

  #pragma unroll
  for (int off = 32; off; off >>= 1) {
    ce_sum  += __shfl_xor(ce_sum, off);
    cnt_sum += __shfl_xor(cnt_sum, off);
  }
  if (lane == 0) { rbuf[wave] = ce_sum; rbuf[4 + wave] = cnt_sum; }
  __syncthreads();
  if (tid == 0) {
    const size_t slot = ((size_t)blockIdx.y * N + blockIdx.x) * 2;
    part[slot + 0] = rbuf[0] + rbuf[1] + rbuf[2] + rbuf[3];
    part[slot + 1] = rbuf[4] + rbuf[5] + rbuf[6] + rbuf[7];
  }
}

// ---------------------------------------------------------------------------
// Kernel 3: finalize — batch b owns slots [b*4N, (b+1)*4N) (4 quarters x N).
// ---------------------------------------------------------------------------
__global__ __launch_bounds__(256) void finalize_kernel(
    const float* __restrict__ part, float* __restrict__ out, int N, int B) {
  __shared__ float red[8];
  const int tid = threadIdx.x, wave = tid >> 6, lane = tid & 63;
  float loss = 0.f, vcount = 0.f;
  const int nper = 4 * N;
  for (int b = 0; b < B; ++b) {
    float ce = 0.f, cnt = 0.f;
    for (int e = tid; e < nper; e += 256) {
      const size_t base = ((size_t)b * nper + e) * 2;
      ce  += part[base + 0];
      cnt += part[base + 1];
    }
    #pragma unroll
    for (int off = 32; off; off >>= 1) {
      ce  += __shfl_xor(ce, off);
      cnt += __shfl_xor(cnt, off);
    }
    if (lane == 0) { red[wave] = ce; red[4 + wave] = cnt; }
    __syncthreads();
    if (tid == 0) {
      const float s = red[0] + red[1] + red[2] + red[3];
      const float c = red[4] + red[5] + red[6] + red[7];
      if (c > 0.f) { loss += s / fmaxf(c, 1.f); vcount += 1.f; }
    }
    __syncthreads();
  }
  if (tid == 0) out[0] = (vcount > 0.f) ? loss / vcount : 0.f;
}

extern "C" void kernel_launch(void* const* d_in, const int* in_sizes, int n_in,
                              void* d_out, int out_size, void* d_ws, size_t ws_size,
                              hipStream_t stream) {
  const float* h_res  = (const float*)d_in[0];
  const float* x_true = (const float*)d_in[1];
  const float* pmask  = (const float*)d_in[2];
  const float* ln_w   = (const float*)d_in[3];
  const float* ln_b   = (const float*)d_in[4];
  const float* wu_w   = (const float*)d_in[5];
  const float* wu_b   = (const float*)d_in[6];
  const float* wv_w   = (const float*)d_in[7];
  const float* wv_b   = (const float*)d_in[8];
  const float* wb_w   = (const float*)d_in[9];
  const float* wb_b   = (const float*)d_in[10];

  const int B  = 2;
  const int N  = in_sizes[2] / B;
  const int BN = B * N;

  // ws: U f32[BN*64] | Vbf bf16[BN*64] | part f32[4B*N*2]
  float* U = (float*)d_ws;
  __hip_bfloat16* Vbf = (__hip_bfloat16*)(U + (size_t)BN * D_LOW);
  float* part = (float*)(Vbf + (size_t)BN * D_LOW);

  lnp_kernel<<<dim3(BN / 16, 2), 256, 0, stream>>>(
      h_res, ln_w, ln_b, wu_w, wu_b, wv_w, wv_b, U, Vbf, N);
  pair_kernel<<<dim3(N, 4 * B), 256, 0, stream>>>(
      U, Vbf, wb_w, wb_b, x_true, pmask, part, N);
  finalize_kernel<<<1, 256, 0, stream>>>(part, (float*)d_out, N, B);
}

// Round 8
// 121.098 us; speedup vs baseline: 1.1088x; 1.1088x over previous
//
#include <hip/hip_runtime.h>
#include <hip/hip_bf16.h>
#include <math.h>

#define D_MODEL 512
#define D_LOW   64
#define NBINS   39
#define LOG2E   1.4426950408889634f
#define LN2     0.6931471805599453f

typedef __attribute__((ext_vector_type(8))) short short8;
typedef __attribute__((ext_vector_type(4))) float floatx4;

// ---------------------------------------------------------------------------
// Kernel 1 (lnp): prep + lnproj fused (r7 version, verified).
// grid = (BN/16, 2) x 256 (4 waves). og: 0 -> U outs (scale=log2e), 1 -> V.
// ---------------------------------------------------------------------------
__global__ __launch_bounds__(256) void lnp_kernel(
    const float* __restrict__ h_res,
    const float* __restrict__ ln_w, const float* __restrict__ ln_b,
    const float* __restrict__ wu_w, const float* __restrict__ wu_b,
    const float* __restrict__ wv_w, const float* __restrict__ wv_b,
    float* __restrict__ U, __hip_bfloat16* __restrict__ Vbf, int N) {
  __shared__ short abuf[16 * 512];          // [kc][q][ln16][8], 16 KB
  __shared__ float sred[4][2][16];          // per-wave (sum,ssq) row partials
  const int tid = threadIdx.x;
  const int wv = tid >> 6, lane = tid & 63;
  const int q = lane >> 4, ln16 = lane & 15;
  const int row0 = blockIdx.x * 16;
  const int og = blockIdx.y;                 // 0 = U half, 1 = V half

  // ---- phase 1a: A tile + stats (wave wv owns kc = 4wv .. 4wv+3) ----
  float sum = 0.f, ssq = 0.f;
  #pragma unroll
  for (int k2 = 0; k2 < 4; ++k2) {
    const int kc = wv * 4 + k2;
    const float* hp = h_res + (size_t)(row0 + ln16) * D_MODEL + kc * 32 + q * 8;
    const floatx4 x0 = *reinterpret_cast<const floatx4*>(hp);
    const floatx4 x1 = *reinterpret_cast<const floatx4*>(hp + 4);
    short8 a;
    #pragma unroll
    for (int e = 0; e < 4; ++e) {
      sum += x0[e]; ssq += x0[e] * x0[e];
      const __hip_bfloat16 hb = __float2bfloat16(x0[e]);
      a[e] = *reinterpret_cast<const short*>(&hb);
    }
    #pragma unroll
    for (int e = 0; e < 4; ++e) {
      sum += x1[e]; ssq += x1[e] * x1[e];
      const __hip_bfloat16 hb = __float2bfloat16(x1[e]);
      a[4 + e] = *reinterpret_cast<const short*>(&hb);
    }
    *reinterpret_cast<short8*>(&abuf[kc * 512 + q * 128 + ln16 * 8]) = a;
  }
  sum += __shfl_xor(sum, 16); sum += __shfl_xor(sum, 32);
  ssq += __shfl_xor(ssq, 16); ssq += __shfl_xor(ssq, 32);
  if (lane < 16) { sred[wv][0][ln16] = sum; sred[wv][1][ln16] = ssq; }

  // ---- phase 1b: fold weights into B-fragments (registers) ----
  const int oloc = wv * 16 + ln16;           // 0..63 within half
  const float scale = og ? 1.0f : LOG2E;
  const float* wrow = (og ? wv_w : wu_w) + (size_t)oloc * D_MODEL;
  short8 bfrag[16];
  float ws = 0.f, sb = 0.f;
  #pragma unroll
  for (int kc = 0; kc < 16; ++kc) {
    const int c0 = kc * 32 + q * 8;
    const floatx4 w0 = *reinterpret_cast<const floatx4*>(wrow + c0);
    const floatx4 w1 = *reinterpret_cast<const floatx4*>(wrow + c0 + 4);
    const floatx4 lw0 = *reinterpret_cast<const floatx4*>(ln_w + c0);
    const floatx4 lw1 = *reinterpret_cast<const floatx4*>(ln_w + c0 + 4);
    const floatx4 lb0 = *reinterpret_cast<const floatx4*>(ln_b + c0);
    const floatx4 lb1 = *reinterpret_cast<const floatx4*>(ln_b + c0 + 4);
    short8 f;
    #pragma unroll
    for (int e = 0; e < 4; ++e) {
      const float t0 = w0[e] * lw0[e] * scale;
      const __hip_bfloat16 h0 = __float2bfloat16(t0);
      f[e] = *reinterpret_cast<const short*>(&h0);
      ws += __bfloat162float(h0);
      sb += w0[e] * lb0[e];

      const float t1 = w1[e] * lw1[e] * scale;
      const __hip_bfloat16 h1 = __float2bfloat16(t1);
      f[4 + e] = *reinterpret_cast<const short*>(&h1);
      ws += __bfloat162float(h1);
      sb += w1[e] * lb1[e];
    }
    bfrag[kc] = f;
  }
  ws += __shfl_xor(ws, 16); ws += __shfl_xor(ws, 32);
  sb += __shfl_xor(sb, 16); sb += __shfl_xor(sb, 32);
  const float bb = scale * ((og ? wv_b[oloc] : wu_b[oloc]) + sb);

  __syncthreads();

  // ---- LN stats for the 4 C-rows this lane writes ----
  float mu_r[4], rs_r[4];
  #pragma unroll
  for (int r = 0; r < 4; ++r) {
    const int row = q * 4 + r;
    float s = 0.f, s2 = 0.f;
    #pragma unroll
    for (int w = 0; w < 4; ++w) { s += sred[w][0][row]; s2 += sred[w][1][row]; }
    const float mu  = s * (1.0f / (float)D_MODEL);
    const float var = s2 * (1.0f / (float)D_MODEL) - mu * mu;
    mu_r[r] = mu;
    rs_r[r] = rsqrtf(var + 1e-5f);
  }

  // ---- phase 2: MFMA over K ----
  floatx4 acc = (floatx4){0.f, 0.f, 0.f, 0.f};
  #pragma unroll
  for (int kc = 0; kc < 16; ++kc) {
    const short8 afr = *reinterpret_cast<const short8*>(
        &abuf[kc * 512 + q * 128 + ln16 * 8]);
    acc = __builtin_amdgcn_mfma_f32_16x16x32_bf16(afr, bfrag[kc], acc, 0, 0, 0);
  }

  #pragma unroll
  for (int r = 0; r < 4; ++r) {
    const int rowg = row0 + q * 4 + r;
    const float val = rs_r[r] * acc[r] - mu_r[r] * rs_r[r] * ws + bb;
    if (og == 0) {
      U[(size_t)rowg * D_LOW + oloc] = val;
    } else {
      Vbf[(size_t)rowg * D_LOW + oloc] = __float2bfloat16(val);
    }
  }
}

// ---------------------------------------------------------------------------
// Kernel 2 (pair v8): grid = BN/4 blocks x 512 threads (8 waves).
// Block owns 4 i-rows; wave wv sweeps j = [wv*96, wv*96+96) (6 tiles of 16)
// for ALL 4 i. V tiles loaded once per wave, reused 4x (fixed-cost
// amortization: every prior structure at 1 i/wave was pinned at 41-48 us
// with VALUBusy ~45% regardless of occupancy 27-43% -> per-wave overhead
// bound). wfrag for the 4 rows built cooperatively in 24 KB LDS, read back
// per-ii (6 ds_read_b128). 384 blocks, ~110 VGPR -> whole grid co-resident
// (2 blocks/CU), zero tail, no ticket (r4 lesson).  Needs N % 128 == 0.
// ---------------------------------------------------------------------------
__global__ __launch_bounds__(512) void pair_kernel(
    const float* __restrict__ U, const __hip_bfloat16* __restrict__ Vbf,
    const float* __restrict__ wb_w, const float* __restrict__ wb_b,
    const float* __restrict__ x_true, const float* __restrict__ pmask,
    float* __restrict__ part, int N) {
  __shared__ short wsh[4 * 6 * 64 * 8];     // 24 KB: [ii][frag][lane][8]
  __shared__ float rbuf[16];
  const int tid = threadIdx.x;
  const int wv = tid >> 6, lane = tid & 63;
  const int q = lane >> 4, ln16 = lane & 15;
  const int i0 = blockIdx.x * 4;            // flattened row base (BN space)
  const int b  = (i0 >= N) ? 1 : 0;         // B == 2, N % 4 == 0
  const int jbase = wv * (N >> 3);          // 96 j per wave
  const int q4 = q * 4;

  // ---- V tiles once per wave (12 loads, reused for all 4 i) ----
  const short* Vp = reinterpret_cast<const short*>(Vbf) + (size_t)b * N * D_LOW;
  short8 v[6][2];
  #pragma unroll
  for (int tl = 0; tl < 6; ++tl) {
    const size_t jr = jbase + tl * 16 + ln16;
    v[tl][0] = *reinterpret_cast<const short8*>(Vp + jr * D_LOW + q * 8);
    v[tl][1] = *reinterpret_cast<const short8*>(Vp + jr * D_LOW + 32 + q * 8);
  }

  // ---- cooperative wfrag build for 4 rows (1536 slots / 512 threads) ----
  for (int s = tid; s < 1536; s += 512) {
    const int ii = s / 384;
    const int rem = s - ii * 384;
    const int fidx = rem >> 6, l = rem & 63;
    const int t = fidx >> 1, ss = fidx & 1;
    const int lq = l >> 4, l16 = l & 15;
    const int n = t * 16 + l16;
    short8 fr = (short8){0, 0, 0, 0, 0, 0, 0, 0};
    if (n < NBINS) {
      const float* up = U + (size_t)(i0 + ii) * D_LOW + ss * 32 + lq * 8;
      const float* wr = wb_w + (size_t)n * D_LOW + ss * 32 + lq * 8;
      const floatx4 u0 = *reinterpret_cast<const floatx4*>(up);
      const floatx4 u1 = *reinterpret_cast<const floatx4*>(up + 4);
      const floatx4 w0 = *reinterpret_cast<const floatx4*>(wr);
      const floatx4 w1 = *reinterpret_cast<const floatx4*>(wr + 4);
      #pragma unroll
      for (int e = 0; e < 4; ++e) {
        const __hip_bfloat16 h0 = __float2bfloat16(u0[e] * w0[e]);
        const __hip_bfloat16 h1 = __float2bfloat16(u1[e] * w1[e]);
        fr[e]     = *reinterpret_cast<const short*>(&h0);
        fr[4 + e] = *reinterpret_cast<const short*>(&h1);
      }
    }
    *reinterpret_cast<short8*>(&wsh[s * 8]) = fr;
  }

  // ---- tbin for 4 i x 6 tiles ----
  float xi0v[4], xi1v[4], xi2v[4], pmiv[4];
  #pragma unroll
  for (int ii = 0; ii < 4; ++ii) {
    const int rowi = i0 + ii;
    xi0v[ii] = x_true[rowi * 3 + 0];
    xi1v[ii] = x_true[rowi * 3 + 1];
    xi2v[ii] = x_true[rowi * 3 + 2];
    pmiv[ii] = pmask[rowi];
  }
  const float BW = (22.0f - 2.0f) / 38.0f;
  int tb[4][6];
  #pragma unroll
  for (int tl = 0; tl < 6; ++tl) {
    const int rowj = b * N + jbase + tl * 16 + ln16;
    const float xj0 = x_true[rowj * 3 + 0];
    const float xj1 = x_true[rowj * 3 + 1];
    const float xj2 = x_true[rowj * 3 + 2];
    const float pmj = pmask[rowj];
    #pragma unroll
    for (int ii = 0; ii < 4; ++ii) {
      const float dx = xi0v[ii] - xj0;
      const float dy = xi1v[ii] - xj1;
      const float dz = xi2v[ii] - xj2;
      const float d  = sqrtf(dx * dx + dy * dy + dz * dz);
      int t = (int)((d - 2.0f) / BW);
      t = t < 0 ? 0 : (t > NBINS - 1 ? NBINS - 1 : t);
      tb[ii][tl] = (pmiv[ii] * pmj > 0.f) ? t : -1;
    }
  }

  floatx4 bias_init[3];
  #pragma unroll
  for (int t = 0; t < 3; ++t)
    #pragma unroll
    for (int r = 0; r < 4; ++r) {
      const int bin = t * 16 + q * 4 + r;
      bias_init[t][r] = (bin < NBINS) ? LOG2E * wb_b[bin] : -INFINITY;
    }

  __syncthreads();

  float ce_sum = 0.f, cnt_sum = 0.f;
  #pragma unroll
  for (int ii = 0; ii < 4; ++ii) {
    short8 wfrag[3][2];
    #pragma unroll
    for (int t = 0; t < 3; ++t)
      #pragma unroll
      for (int s = 0; s < 2; ++s)
        wfrag[t][s] = *reinterpret_cast<const short8*>(
            &wsh[((ii * 6 + t * 2 + s) * 64 + lane) * 8]);

    #pragma unroll
    for (int tl = 0; tl < 6; ++tl) {
      floatx4 f[3];
      #pragma unroll
      for (int t = 0; t < 3; ++t) {
        floatx4 a = bias_init[t];
        a = __builtin_amdgcn_mfma_f32_16x16x32_bf16(wfrag[t][0], v[tl][0], a, 0, 0, 0);
        a = __builtin_amdgcn_mfma_f32_16x16x32_bf16(wfrag[t][1], v[tl][1], a, 0, 0, 0);
        f[t] = a;
      }

      const int tbv = tb[ii][tl];
      const int tbq = tbv - q4;
      float s0 = 0.f, s1 = 0.f, s2 = 0.f, s3 = 0.f, lt = 0.f;
      #pragma unroll
      for (int t = 0; t < 3; ++t) {
        const floatx4 fv = f[t];
        s0 += __builtin_amdgcn_exp2f(fv[0]);
        s1 += __builtin_amdgcn_exp2f(fv[1]);
        s2 += __builtin_amdgcn_exp2f(fv[2]);
        s3 += __builtin_amdgcn_exp2f(fv[3]);
        lt += (tbq == t * 16 + 0) ? fv[0] : 0.f;
        lt += (tbq == t * 16 + 1) ? fv[1] : 0.f;
        lt += (tbq == t * 16 + 2) ? fv[2] : 0.f;
        lt += (tbq == t * 16 + 3) ? fv[3] : 0.f;
      }
      float ssum = (s0 + s1) + (s2 + s3);
      ssum += __shfl_xor(ssum, 16); ssum += __shfl_xor(ssum, 32);
      const float ok = (tbv >= 0) ? 1.f : 0.f;
      ce_sum  += ok * LN2 * (__builtin_amdgcn_logf(ssum) - 4.0f * lt);
      cnt_sum += ok;
    }
  }

  #pragma unroll
  for (int off = 32; off; off >>= 1) {
    ce_sum  += __shfl_xor(ce_sum, off);
    cnt_sum += __shfl_xor(cnt_sum, off);
  }
  if (lane == 0) { rbuf[wv] = ce_sum; rbuf[8 + wv] = cnt_sum; }
  __syncthreads();
  if (tid == 0) {
    float ce = 0.f, cnt = 0.f;
    #pragma unroll
    for (int w = 0; w < 8; ++w) { ce += rbuf[w]; cnt += rbuf[8 + w]; }
    const size_t slot = (size_t)blockIdx.x * 2;
    part[slot + 0] = ce;
    part[slot + 1] = cnt;
  }
}

// ---------------------------------------------------------------------------
// Kernel 3: finalize — batch b owns slots [b*(N/4), (b+1)*(N/4)).
// ---------------------------------------------------------------------------
__global__ __launch_bounds__(256) void finalize_kernel(
    const float* __restrict__ part, float* __restrict__ out, int N, int B) {
  __shared__ float red[8];
  const int tid = threadIdx.x, wave = tid >> 6, lane = tid & 63;
  float loss = 0.f, vcount = 0.f;
  const int nper = N / 4;
  for (int b = 0; b < B; ++b) {
    float ce = 0.f, cnt = 0.f;
    for (int e = tid; e < nper; e += 256) {
      const size_t base = ((size_t)b * nper + e) * 2;
      ce  += part[base + 0];
      cnt += part[base + 1];
    }
    #pragma unroll
    for (int off = 32; off; off >>= 1) {
      ce  += __shfl_xor(ce, off);
      cnt += __shfl_xor(cnt, off);
    }
    if (lane == 0) { red[wave] = ce; red[4 + wave] = cnt; }
    __syncthreads();
    if (tid == 0) {
      const float s = red[0] + red[1] + red[2] + red[3];
      const float c = red[4] + red[5] + red[6] + red[7];
      if (c > 0.f) { loss += s / fmaxf(c, 1.f); vcount += 1.f; }
    }
    __syncthreads();
  }
  if (tid == 0) out[0] = (vcount > 0.f) ? loss / vcount : 0.f;
}

extern "C" void kernel_launch(void* const* d_in, const int* in_sizes, int n_in,
                              void* d_out, int out_size, void* d_ws, size_t ws_size,
                              hipStream_t stream) {
  const float* h_res  = (const float*)d_in[0];
  const float* x_true = (const float*)d_in[1];
  const float* pmask  = (const float*)d_in[2];
  const float* ln_w   = (const float*)d_in[3];
  const float* ln_b   = (const float*)d_in[4];
  const float* wu_w   = (const float*)d_in[5];
  const float* wu_b   = (const float*)d_in[6];
  const float* wv_w   = (const float*)d_in[7];
  const float* wv_b   = (const float*)d_in[8];
  const float* wb_w   = (const float*)d_in[9];
  const float* wb_b   = (const float*)d_in[10];

  const int B  = 2;
  const int N  = in_sizes[2] / B;
  const int BN = B * N;

  // ws: U f32[BN*64] | Vbf bf16[BN*64] | part f32[(BN/4)*2]
  float* U = (float*)d_ws;
  __hip_bfloat16* Vbf = (__hip_bfloat16*)(U + (size_t)BN * D_LOW);
  float* part = (float*)(Vbf + (size_t)BN * D_LOW);

  lnp_kernel<<<dim3(BN / 16, 2), 256, 0, stream>>>(
      h_res, ln_w, ln_b, wu_w, wu_b, wv_w, wv_b, U, Vbf, N);
  pair_kernel<<<BN / 4, 512, 0, stream>>>(
      U, Vbf, wb_w, wb_b, x_true, pmask, part, N);
  finalize_kernel<<<1, 256, 0, stream>>>(part, (float*)d_out, N, B);
}